// Round 4
// baseline (513.384 us; speedup 1.0000x reference)
//
#include <hip/hip_runtime.h>
#include <hip/hip_bf16.h>

#define N_NODES 50000
#define N_EDGES 1600000

typedef __attribute__((ext_vector_type(8))) short short8;
typedef __attribute__((ext_vector_type(4))) float f32x4;

__device__ __forceinline__ unsigned short f2bf(float f) {
  union { float f; unsigned int i; } v; v.f = f;
  unsigned int i = v.i;
  unsigned int r = i + 0x7FFFu + ((i >> 16) & 1u);
  return (unsigned short)(r >> 16);
}

// ---------------- Kernel 1: x = h @ W  (fp32 in, bf16 MFMA, f32 out) -------
// Proven equivalent to scalar reference in R2/R3 bisect (identical output).
// A frag (16x16x32): lane holds A[m=lane&15][k=quad*8+j], j=0..7
// B frag: lane holds B[k=quad*8+j][n=lane&15]  (from W^T staged in LDS)
// C/D:    col=lane&15, row=quad*4+reg
__global__ __launch_bounds__(256) void k_x(const float* __restrict__ hmat,
                                           const float* __restrict__ Wmat,
                                           float* __restrict__ x) {
  __shared__ unsigned short Wt[64 * 264];  // Wt[n][k], row stride 264 (16B-aligned)
  const int t = threadIdx.x;
  for (int idx = t; idx < 64 * 256; idx += 256) {
    int k = idx >> 6, n = idx & 63;        // global read coalesced (idx = k*64+n)
    Wt[n * 264 + k] = f2bf(Wmat[idx]);
  }
  __syncthreads();
  const int wave = t >> 6, lane = t & 63;
  const int quad = lane >> 4, l16 = lane & 15;
  const int m0 = blockIdx.x * 64 + wave * 16;
  int arow = m0 + l16; if (arow >= N_NODES) arow = N_NODES - 1;  // clamp: rows independent
  f32x4 c[4] = {{0,0,0,0},{0,0,0,0},{0,0,0,0},{0,0,0,0}};
  const float* aptr = hmat + (size_t)arow * 256 + quad * 8;
  #pragma unroll
  for (int kb = 0; kb < 8; ++kb) {
    f32x4 a0 = *(const f32x4*)(aptr + kb * 32);
    f32x4 a1 = *(const f32x4*)(aptr + kb * 32 + 4);
    short8 a;
    a[0] = (short)f2bf(a0[0]); a[1] = (short)f2bf(a0[1]);
    a[2] = (short)f2bf(a0[2]); a[3] = (short)f2bf(a0[3]);
    a[4] = (short)f2bf(a1[0]); a[5] = (short)f2bf(a1[1]);
    a[6] = (short)f2bf(a1[2]); a[7] = (short)f2bf(a1[3]);
    #pragma unroll
    for (int nt = 0; nt < 4; ++nt) {
      int n = nt * 16 + l16;
      short8 b = *(const short8*)(&Wt[n * 264 + kb * 32 + quad * 8]);
      c[nt] = __builtin_amdgcn_mfma_f32_16x16x32_bf16(a, b, c[nt], 0, 0, 0);
    }
  }
  #pragma unroll
  for (int nt = 0; nt < 4; ++nt) {
    #pragma unroll
    for (int r = 0; r < 4; ++r) {
      int grow = m0 + quad * 4 + r;
      if (grow < N_NODES) x[grow * 64 + nt * 16 + l16] = c[nt][r];
    }
  }
}

// ---------------- Kernel 2: el = x@Wl^T, er = x@Wr^T (wave per row) ---------
__global__ __launch_bounds__(256) void k_eler(const float* __restrict__ x,
    const float* __restrict__ Wl, const float* __restrict__ Wr,
    float* __restrict__ el, float* __restrict__ er) {
  const int lane = threadIdx.x & 63;
  const int gw = (blockIdx.x * 256 + threadIdx.x) >> 6;
  const int nw = gridDim.x * 4;
  float wl[4], wr[4];
  #pragma unroll
  for (int hh = 0; hh < 4; ++hh) {
    wl[hh] = Wl[hh * 64 + lane];
    wr[hh] = Wr[hh * 64 + lane];
  }
  for (int r = gw; r < N_NODES; r += nw) {
    float xv = x[r * 64 + lane];
    float p[4], q[4];
    #pragma unroll
    for (int hh = 0; hh < 4; ++hh) { p[hh] = xv * wl[hh]; q[hh] = xv * wr[hh]; }
    #pragma unroll
    for (int off = 32; off > 0; off >>= 1) {
      #pragma unroll
      for (int hh = 0; hh < 4; ++hh) {
        p[hh] += __shfl_xor(p[hh], off, 64);
        q[hh] += __shfl_xor(q[hh], off, 64);
      }
    }
    if (lane == 0) {
      f32x4 pv = {p[0], p[1], p[2], p[3]};
      f32x4 qv = {q[0], q[1], q[2], q[3]};
      ((f32x4*)el)[r] = pv;
      ((f32x4*)er)[r] = qv;
    }
  }
}

// ---------------- CSR build: histogram -> scan -> scatter -------------------
__global__ __launch_bounds__(256) void k_hist(const int* __restrict__ ei,
                                              int* __restrict__ deg) {
  int e = blockIdx.x * 256 + threadIdx.x;
  if (e < N_EDGES) atomicAdd(&deg[ei[e]], 1);
}

__global__ __launch_bounds__(256) void k_s1(const int* __restrict__ deg,
                                            int* __restrict__ bsum) {
  const int lane = threadIdx.x & 63, wv = threadIdx.x >> 6;
  int v = deg[blockIdx.x * 256 + threadIdx.x];  // deg zero-padded to 50176
  #pragma unroll
  for (int off = 32; off > 0; off >>= 1) v += __shfl_xor(v, off, 64);
  __shared__ int sm[4];
  if (lane == 0) sm[wv] = v;
  __syncthreads();
  if (threadIdx.x == 0) bsum[blockIdx.x] = sm[0] + sm[1] + sm[2] + sm[3];
}

__global__ __launch_bounds__(256) void k_s2(const int* __restrict__ bsum,
                                            int* __restrict__ boff) {
  __shared__ int buf[256];
  const int t = threadIdx.x;
  int v = (t < 196) ? bsum[t] : 0;
  buf[t] = v; __syncthreads();
  for (int off = 1; off < 256; off <<= 1) {
    int u = (t >= off) ? buf[t - off] : 0;
    __syncthreads();
    buf[t] += u;
    __syncthreads();
  }
  if (t < 196) boff[t] = buf[t] - v;  // exclusive
}

__global__ __launch_bounds__(256) void k_s3(const int* __restrict__ deg,
                                            const int* __restrict__ boff,
                                            int* __restrict__ rs,
                                            int* __restrict__ cursor) {
  __shared__ int buf[256];
  const int t = threadIdx.x;
  const int i = blockIdx.x * 256 + t;
  int v = deg[i];
  buf[t] = v; __syncthreads();
  for (int off = 1; off < 256; off <<= 1) {
    int u = (t >= off) ? buf[t - off] : 0;
    __syncthreads();
    buf[t] += u;
    __syncthreads();
  }
  int r = boff[blockIdx.x] + buf[t] - v;
  if (i <= N_NODES) rs[i] = r;
  if (i < N_NODES) cursor[i] = r;
}

__global__ __launch_bounds__(256) void k_scatter(const int* __restrict__ ei,
                                                 int* __restrict__ cursor,
                                                 int* __restrict__ csr) {
  int e = blockIdx.x * 256 + threadIdx.x;
  if (e < N_EDGES) {
    int s = ei[e];
    int pos = atomicAdd(&cursor[s], 1);
    csr[pos] = ei[N_EDGES + e];
  }
}

// ---------------- Kernel 5: fused softmax-normalize + SpMM + ELU ------------
// One wave per node, lane = output dim. out[n][h][d] = elu(num_h[d]/den_h + b[d])
__global__ __launch_bounds__(256) void k_agg(const float* __restrict__ x,
    const float* __restrict__ el, const float* __restrict__ er,
    const int* __restrict__ rs, const int* __restrict__ csr,
    const float* __restrict__ bvec, float* __restrict__ out) {
  const int node = (blockIdx.x * 256 + threadIdx.x) >> 6;
  const int lane = threadIdx.x & 63;
  if (node >= N_NODES) return;
  f32x4 el4 = ((const f32x4*)el)[node];
  float n0 = 0.f, n1 = 0.f, n2 = 0.f, n3 = 0.f;
  float d0 = 0.f, d1 = 0.f, d2 = 0.f, d3 = 0.f;
  const int j0 = rs[node], j1 = rs[node + 1];
  for (int j = j0; j < j1; ++j) {
    int dn = csr[j];                            // wave-uniform broadcast
    f32x4 er4 = ((const f32x4*)er)[dn];         // 16B broadcast
    float xv = x[dn * 64 + lane];               // coalesced 256B gather
    float t0 = el4[0] + er4[0]; t0 = (t0 >= 0.f) ? t0 : 0.2f * t0; float e0 = __expf(t0);
    float t1 = el4[1] + er4[1]; t1 = (t1 >= 0.f) ? t1 : 0.2f * t1; float e1 = __expf(t1);
    float t2 = el4[2] + er4[2]; t2 = (t2 >= 0.f) ? t2 : 0.2f * t2; float e2 = __expf(t2);
    float t3 = el4[3] + er4[3]; t3 = (t3 >= 0.f) ? t3 : 0.2f * t3; float e3 = __expf(t3);
    d0 += e0; d1 += e1; d2 += e2; d3 += e3;
    n0 = fmaf(e0, xv, n0); n1 = fmaf(e1, xv, n1);
    n2 = fmaf(e2, xv, n2); n3 = fmaf(e3, xv, n3);
  }
  float bv = bvec[lane];
  size_t ob = (size_t)node * 256 + lane;
  float o;
  o = n0 / fmaxf(d0, 1e-12f) + bv; o = (o > 0.f) ? o : (__expf(o) - 1.f); out[ob      ] = o;
  o = n1 / fmaxf(d1, 1e-12f) + bv; o = (o > 0.f) ? o : (__expf(o) - 1.f); out[ob +  64] = o;
  o = n2 / fmaxf(d2, 1e-12f) + bv; o = (o > 0.f) ? o : (__expf(o) - 1.f); out[ob + 128] = o;
  o = n3 / fmaxf(d3, 1e-12f) + bv; o = (o > 0.f) ? o : (__expf(o) - 1.f); out[ob + 192] = o;
}

// ---------------- Launch ----------------------------------------------------
extern "C" void kernel_launch(void* const* d_in, const int* in_sizes, int n_in,
                              void* d_out, int out_size, void* d_ws, size_t ws_size,
                              hipStream_t stream) {
  const float* h  = (const float*)d_in[0];
  const float* W  = (const float*)d_in[1];
  const float* Wl = (const float*)d_in[2];
  const float* Wr = (const float*)d_in[3];
  const float* b  = (const float*)d_in[4];
  const int*   ei = (const int*)d_in[5];
  float* out = (float*)d_out;   // reference output dtype is float32

  char* ws = (char*)d_ws;
  float* x      = (float*)(ws + 0);          // 50000*64*4   = 12,800,000
  float* el     = (float*)(ws + 12800000);   // 50000*4*4    =    800,000
  float* er     = (float*)(ws + 13600000);   // 50000*4*4    =    800,000
  int*   deg    = (int*)  (ws + 14400000);   // 50176*4      =    200,704
  int*   cursor = (int*)  (ws + 14600704);   // 50176*4      =    200,704
  int*   rs     = (int*)  (ws + 14801408);   // 50001*4 (pad)=    200,960
  int*   bsum   = (int*)  (ws + 15002368);   // 256*4
  int*   boff   = (int*)  (ws + 15003392);   // 256*4
  int*   csr    = (int*)  (ws + 15004416);   // 1.6M*4       =  6,400,000
  (void)ws_size; (void)in_sizes; (void)n_in; (void)out_size;

  hipMemsetAsync(deg, 0, 50176 * sizeof(int), stream);

  k_x      <<<782,   256, 0, stream>>>(h, W, x);
  k_eler   <<<782,   256, 0, stream>>>(x, Wl, Wr, el, er);
  k_hist   <<<6250,  256, 0, stream>>>(ei, deg);
  k_s1     <<<196,   256, 0, stream>>>(deg, bsum);
  k_s2     <<<1,     256, 0, stream>>>(bsum, boff);
  k_s3     <<<196,   256, 0, stream>>>(deg, boff, rs, cursor);
  k_scatter<<<6250,  256, 0, stream>>>(ei, cursor, csr);
  k_agg    <<<12500, 256, 0, stream>>>(x, el, er, rs, csr, b, out);
}

// Round 5
// 397.800 us; speedup vs baseline: 1.2906x; 1.2906x over previous
//
#include <hip/hip_runtime.h>
#include <hip/hip_bf16.h>

#define N_NODES 50000
#define N_EDGES 1600000

typedef __attribute__((ext_vector_type(8))) short short8;
typedef __attribute__((ext_vector_type(4))) float f32x4;

__device__ __forceinline__ unsigned short f2bf(float f) {
  union { float f; unsigned int i; } v; v.f = f;
  unsigned int i = v.i;
  unsigned int r = i + 0x7FFFu + ((i >> 16) & 1u);
  return (unsigned short)(r >> 16);
}

// ---------------- Kernel 1: x = h @ W  (fp32 in, bf16 MFMA, f32 out) -------
__global__ __launch_bounds__(256) void k_x(const float* __restrict__ hmat,
                                           const float* __restrict__ Wmat,
                                           float* __restrict__ x) {
  __shared__ unsigned short Wt[64 * 264];  // Wt[n][k], row stride 264 (16B-aligned)
  const int t = threadIdx.x;
  for (int idx = t; idx < 64 * 256; idx += 256) {
    int k = idx >> 6, n = idx & 63;        // global read coalesced (idx = k*64+n)
    Wt[n * 264 + k] = f2bf(Wmat[idx]);
  }
  __syncthreads();
  const int wave = t >> 6, lane = t & 63;
  const int quad = lane >> 4, l16 = lane & 15;
  const int m0 = blockIdx.x * 64 + wave * 16;
  int arow = m0 + l16; if (arow >= N_NODES) arow = N_NODES - 1;  // clamp: rows independent
  f32x4 c[4] = {{0,0,0,0},{0,0,0,0},{0,0,0,0},{0,0,0,0}};
  const float* aptr = hmat + (size_t)arow * 256 + quad * 8;
  #pragma unroll
  for (int kb = 0; kb < 8; ++kb) {
    f32x4 a0 = *(const f32x4*)(aptr + kb * 32);
    f32x4 a1 = *(const f32x4*)(aptr + kb * 32 + 4);
    short8 a;
    a[0] = (short)f2bf(a0[0]); a[1] = (short)f2bf(a0[1]);
    a[2] = (short)f2bf(a0[2]); a[3] = (short)f2bf(a0[3]);
    a[4] = (short)f2bf(a1[0]); a[5] = (short)f2bf(a1[1]);
    a[6] = (short)f2bf(a1[2]); a[7] = (short)f2bf(a1[3]);
    #pragma unroll
    for (int nt = 0; nt < 4; ++nt) {
      int n = nt * 16 + l16;
      short8 b = *(const short8*)(&Wt[n * 264 + kb * 32 + quad * 8]);
      c[nt] = __builtin_amdgcn_mfma_f32_16x16x32_bf16(a, b, c[nt], 0, 0, 0);
    }
  }
  #pragma unroll
  for (int nt = 0; nt < 4; ++nt) {
    #pragma unroll
    for (int r = 0; r < 4; ++r) {
      int grow = m0 + quad * 4 + r;
      if (grow < N_NODES) x[grow * 64 + nt * 16 + l16] = c[nt][r];
    }
  }
}

// ---------------- Kernel 2: el = x@Wl^T, er = x@Wr^T (wave per row) ---------
__global__ __launch_bounds__(256) void k_eler(const float* __restrict__ x,
    const float* __restrict__ Wl, const float* __restrict__ Wr,
    float* __restrict__ el, float* __restrict__ er) {
  const int lane = threadIdx.x & 63;
  const int gw = (blockIdx.x * 256 + threadIdx.x) >> 6;
  const int nw = gridDim.x * 4;
  float wl[4], wr[4];
  #pragma unroll
  for (int hh = 0; hh < 4; ++hh) {
    wl[hh] = Wl[hh * 64 + lane];
    wr[hh] = Wr[hh * 64 + lane];
  }
  for (int r = gw; r < N_NODES; r += nw) {
    float xv = x[r * 64 + lane];
    float p[4], q[4];
    #pragma unroll
    for (int hh = 0; hh < 4; ++hh) { p[hh] = xv * wl[hh]; q[hh] = xv * wr[hh]; }
    #pragma unroll
    for (int off = 32; off > 0; off >>= 1) {
      #pragma unroll
      for (int hh = 0; hh < 4; ++hh) {
        p[hh] += __shfl_xor(p[hh], off, 64);
        q[hh] += __shfl_xor(q[hh], off, 64);
      }
    }
    if (lane == 0) {
      f32x4 pv = {p[0], p[1], p[2], p[3]};
      f32x4 qv = {q[0], q[1], q[2], q[3]};
      ((f32x4*)el)[r] = pv;
      ((f32x4*)er)[r] = qv;
    }
  }
}

// ---------------- CSR build: histogram -> scan -> scatter -------------------
__global__ __launch_bounds__(256) void k_hist(const int* __restrict__ ei,
                                              int* __restrict__ deg) {
  int e = blockIdx.x * 256 + threadIdx.x;
  if (e < N_EDGES) atomicAdd(&deg[ei[e]], 1);
}

__global__ __launch_bounds__(256) void k_s1(const int* __restrict__ deg,
                                            int* __restrict__ bsum) {
  const int lane = threadIdx.x & 63, wv = threadIdx.x >> 6;
  int v = deg[blockIdx.x * 256 + threadIdx.x];  // deg zero-padded to 50176
  #pragma unroll
  for (int off = 32; off > 0; off >>= 1) v += __shfl_xor(v, off, 64);
  __shared__ int sm[4];
  if (lane == 0) sm[wv] = v;
  __syncthreads();
  if (threadIdx.x == 0) bsum[blockIdx.x] = sm[0] + sm[1] + sm[2] + sm[3];
}

__global__ __launch_bounds__(256) void k_s2(const int* __restrict__ bsum,
                                            int* __restrict__ boff) {
  __shared__ int buf[256];
  const int t = threadIdx.x;
  int v = (t < 196) ? bsum[t] : 0;
  buf[t] = v; __syncthreads();
  for (int off = 1; off < 256; off <<= 1) {
    int u = (t >= off) ? buf[t - off] : 0;
    __syncthreads();
    buf[t] += u;
    __syncthreads();
  }
  if (t < 196) boff[t] = buf[t] - v;  // exclusive
}

__global__ __launch_bounds__(256) void k_s3(const int* __restrict__ deg,
                                            const int* __restrict__ boff,
                                            int* __restrict__ rs,
                                            int* __restrict__ cursor) {
  __shared__ int buf[256];
  const int t = threadIdx.x;
  const int i = blockIdx.x * 256 + t;
  int v = deg[i];
  buf[t] = v; __syncthreads();
  for (int off = 1; off < 256; off <<= 1) {
    int u = (t >= off) ? buf[t - off] : 0;
    __syncthreads();
    buf[t] += u;
    __syncthreads();
  }
  int r = boff[blockIdx.x] + buf[t] - v;
  if (i <= N_NODES) rs[i] = r;
  if (i < N_NODES) cursor[i] = r;
}

// Scatter + per-edge attention weight: w[h] = exp(leaky(el[s][h] + er[d][h]))
// Moves the wave-uniform exp work out of k_agg into edge-parallel form.
__global__ __launch_bounds__(256) void k_scatter(const int* __restrict__ ei,
                                                 int* __restrict__ cursor,
                                                 const float* __restrict__ el,
                                                 const float* __restrict__ er,
                                                 int* __restrict__ csr,
                                                 f32x4* __restrict__ wb) {
  int e = blockIdx.x * 256 + threadIdx.x;
  if (e < N_EDGES) {
    int s = ei[e];
    int d = ei[N_EDGES + e];
    int pos = atomicAdd(&cursor[s], 1);
    csr[pos] = d;
    f32x4 a = ((const f32x4*)el)[s];   // L2-resident (800 KB)
    f32x4 b = ((const f32x4*)er)[d];
    f32x4 w;
    #pragma unroll
    for (int hh = 0; hh < 4; ++hh) {
      float t = a[hh] + b[hh];
      t = (t >= 0.f) ? t : 0.2f * t;
      w[hh] = __expf(t);
    }
    wb[pos] = w;
  }
}

// ---------------- Kernel 5: fused normalize + SpMM + ELU --------------------
// One wave per node, lane = output dim. Weights precomputed in wb.
__global__ __launch_bounds__(256) void k_agg(const float* __restrict__ x,
    const int* __restrict__ rs, const int* __restrict__ csr,
    const f32x4* __restrict__ wb,
    const float* __restrict__ bvec, float* __restrict__ out) {
  const int node = (blockIdx.x * 256 + threadIdx.x) >> 6;
  const int lane = threadIdx.x & 63;
  if (node >= N_NODES) return;
  float n0 = 0.f, n1 = 0.f, n2 = 0.f, n3 = 0.f;
  float d0 = 0.f, d1 = 0.f, d2 = 0.f, d3 = 0.f;
  const int j0 = rs[node], j1 = rs[node + 1];
  #pragma unroll 4
  for (int j = j0; j < j1; ++j) {
    int dn = csr[j];                  // wave-uniform broadcast
    f32x4 w = wb[j];                  // 16B broadcast
    float xv = x[dn * 64 + lane];     // coalesced 256B gather
    d0 += w[0]; d1 += w[1]; d2 += w[2]; d3 += w[3];
    n0 = fmaf(w[0], xv, n0); n1 = fmaf(w[1], xv, n1);
    n2 = fmaf(w[2], xv, n2); n3 = fmaf(w[3], xv, n3);
  }
  float bv = bvec[lane];
  size_t ob = (size_t)node * 256 + lane;
  float o;
  o = n0 / fmaxf(d0, 1e-12f) + bv; o = (o > 0.f) ? o : (__expf(o) - 1.f); out[ob      ] = o;
  o = n1 / fmaxf(d1, 1e-12f) + bv; o = (o > 0.f) ? o : (__expf(o) - 1.f); out[ob +  64] = o;
  o = n2 / fmaxf(d2, 1e-12f) + bv; o = (o > 0.f) ? o : (__expf(o) - 1.f); out[ob + 128] = o;
  o = n3 / fmaxf(d3, 1e-12f) + bv; o = (o > 0.f) ? o : (__expf(o) - 1.f); out[ob + 192] = o;
}

// ---------------- Launch ----------------------------------------------------
extern "C" void kernel_launch(void* const* d_in, const int* in_sizes, int n_in,
                              void* d_out, int out_size, void* d_ws, size_t ws_size,
                              hipStream_t stream) {
  const float* h  = (const float*)d_in[0];
  const float* W  = (const float*)d_in[1];
  const float* Wl = (const float*)d_in[2];
  const float* Wr = (const float*)d_in[3];
  const float* b  = (const float*)d_in[4];
  const int*   ei = (const int*)d_in[5];
  float* out = (float*)d_out;   // reference output dtype is float32

  char* ws = (char*)d_ws;
  float* x      = (float*)(ws + 0);          // 50000*64*4   = 12,800,000
  float* el     = (float*)(ws + 12800000);   // 50000*4*4    =    800,000
  float* er     = (float*)(ws + 13600000);   // 50000*4*4    =    800,000
  int*   deg    = (int*)  (ws + 14400000);   // 50176*4      =    200,704
  int*   cursor = (int*)  (ws + 14600704);   // 50176*4      =    200,704
  int*   rs     = (int*)  (ws + 14801408);   // 50001*4 (pad)=    200,960
  int*   bsum   = (int*)  (ws + 15002368);   // 256*4
  int*   boff   = (int*)  (ws + 15003392);   // 256*4
  int*   csr    = (int*)  (ws + 15004416);   // 1.6M*4       =  6,400,000
  f32x4* wb     = (f32x4*)(ws + 21404416);   // 1.6M*16      = 25,600,000 (end ~47.0 MB)
  (void)ws_size; (void)in_sizes; (void)n_in; (void)out_size;

  hipMemsetAsync(deg, 0, 50176 * sizeof(int), stream);

  k_x      <<<782,   256, 0, stream>>>(h, W, x);
  k_eler   <<<782,   256, 0, stream>>>(x, Wl, Wr, el, er);
  k_hist   <<<6250,  256, 0, stream>>>(ei, deg);
  k_s1     <<<196,   256, 0, stream>>>(deg, bsum);
  k_s2     <<<1,     256, 0, stream>>>(bsum, boff);
  k_s3     <<<196,   256, 0, stream>>>(deg, boff, rs, cursor);
  k_scatter<<<6250,  256, 0, stream>>>(ei, cursor, el, er, csr, wb);
  k_agg    <<<12500, 256, 0, stream>>>(x, rs, csr, wb, b, out);
}

// Round 6
// 378.457 us; speedup vs baseline: 1.3565x; 1.0511x over previous
//
#include <hip/hip_runtime.h>
#include <hip/hip_bf16.h>
#include <hip/hip_fp16.h>

#define N_NODES 50000
#define N_EDGES 1600000

typedef __attribute__((ext_vector_type(8))) short short8;
typedef __attribute__((ext_vector_type(4))) float f32x4;

__device__ __forceinline__ unsigned short f2bf(float f) {
  union { float f; unsigned int i; } v; v.f = f;
  unsigned int i = v.i;
  unsigned int r = i + 0x7FFFu + ((i >> 16) & 1u);
  return (unsigned short)(r >> 16);
}

// ---------------- Kernel 1: x = h @ W  (fp32 in, bf16 MFMA, f32 out) -------
__global__ __launch_bounds__(256) void k_x(const float* __restrict__ hmat,
                                           const float* __restrict__ Wmat,
                                           float* __restrict__ x) {
  __shared__ unsigned short Wt[64 * 264];  // Wt[n][k], row stride 264 (16B-aligned)
  const int t = threadIdx.x;
  for (int idx = t; idx < 64 * 256; idx += 256) {
    int k = idx >> 6, n = idx & 63;        // global read coalesced (idx = k*64+n)
    Wt[n * 264 + k] = f2bf(Wmat[idx]);
  }
  __syncthreads();
  const int wave = t >> 6, lane = t & 63;
  const int quad = lane >> 4, l16 = lane & 15;
  const int m0 = blockIdx.x * 64 + wave * 16;
  int arow = m0 + l16; if (arow >= N_NODES) arow = N_NODES - 1;  // clamp: rows independent
  f32x4 c[4] = {{0,0,0,0},{0,0,0,0},{0,0,0,0},{0,0,0,0}};
  const float* aptr = hmat + (size_t)arow * 256 + quad * 8;
  #pragma unroll
  for (int kb = 0; kb < 8; ++kb) {
    f32x4 a0 = *(const f32x4*)(aptr + kb * 32);
    f32x4 a1 = *(const f32x4*)(aptr + kb * 32 + 4);
    short8 a;
    a[0] = (short)f2bf(a0[0]); a[1] = (short)f2bf(a0[1]);
    a[2] = (short)f2bf(a0[2]); a[3] = (short)f2bf(a0[3]);
    a[4] = (short)f2bf(a1[0]); a[5] = (short)f2bf(a1[1]);
    a[6] = (short)f2bf(a1[2]); a[7] = (short)f2bf(a1[3]);
    #pragma unroll
    for (int nt = 0; nt < 4; ++nt) {
      int n = nt * 16 + l16;
      short8 b = *(const short8*)(&Wt[n * 264 + kb * 32 + quad * 8]);
      c[nt] = __builtin_amdgcn_mfma_f32_16x16x32_bf16(a, b, c[nt], 0, 0, 0);
    }
  }
  #pragma unroll
  for (int nt = 0; nt < 4; ++nt) {
    #pragma unroll
    for (int r = 0; r < 4; ++r) {
      int grow = m0 + quad * 4 + r;
      if (grow < N_NODES) x[grow * 64 + nt * 16 + l16] = c[nt][r];
    }
  }
}

// ---------------- Kernel 2: el = x@Wl^T, er = x@Wr^T (wave per row) ---------
__global__ __launch_bounds__(256) void k_eler(const float* __restrict__ x,
    const float* __restrict__ Wl, const float* __restrict__ Wr,
    float* __restrict__ el, float* __restrict__ er) {
  const int lane = threadIdx.x & 63;
  const int gw = (blockIdx.x * 256 + threadIdx.x) >> 6;
  const int nw = gridDim.x * 4;
  float wl[4], wr[4];
  #pragma unroll
  for (int hh = 0; hh < 4; ++hh) {
    wl[hh] = Wl[hh * 64 + lane];
    wr[hh] = Wr[hh * 64 + lane];
  }
  for (int r = gw; r < N_NODES; r += nw) {
    float xv = x[r * 64 + lane];
    float p[4], q[4];
    #pragma unroll
    for (int hh = 0; hh < 4; ++hh) { p[hh] = xv * wl[hh]; q[hh] = xv * wr[hh]; }
    #pragma unroll
    for (int off = 32; off > 0; off >>= 1) {
      #pragma unroll
      for (int hh = 0; hh < 4; ++hh) {
        p[hh] += __shfl_xor(p[hh], off, 64);
        q[hh] += __shfl_xor(q[hh], off, 64);
      }
    }
    if (lane == 0) {
      f32x4 pv = {p[0], p[1], p[2], p[3]};
      f32x4 qv = {q[0], q[1], q[2], q[3]};
      ((f32x4*)el)[r] = pv;
      ((f32x4*)er)[r] = qv;
    }
  }
}

// ---------------- CSR build: histogram -> scan -> scatter -------------------
__global__ __launch_bounds__(256) void k_hist(const int* __restrict__ ei,
                                              int* __restrict__ deg) {
  int e = blockIdx.x * 256 + threadIdx.x;
  if (e < N_EDGES) atomicAdd(&deg[ei[e]], 1);
}

__global__ __launch_bounds__(256) void k_s1(const int* __restrict__ deg,
                                            int* __restrict__ bsum) {
  const int lane = threadIdx.x & 63, wv = threadIdx.x >> 6;
  int v = deg[blockIdx.x * 256 + threadIdx.x];  // deg zero-padded to 50176
  #pragma unroll
  for (int off = 32; off > 0; off >>= 1) v += __shfl_xor(v, off, 64);
  __shared__ int sm[4];
  if (lane == 0) sm[wv] = v;
  __syncthreads();
  if (threadIdx.x == 0) bsum[blockIdx.x] = sm[0] + sm[1] + sm[2] + sm[3];
}

__global__ __launch_bounds__(256) void k_s2(const int* __restrict__ bsum,
                                            int* __restrict__ boff) {
  __shared__ int buf[256];
  const int t = threadIdx.x;
  int v = (t < 196) ? bsum[t] : 0;
  buf[t] = v; __syncthreads();
  for (int off = 1; off < 256; off <<= 1) {
    int u = (t >= off) ? buf[t - off] : 0;
    __syncthreads();
    buf[t] += u;
    __syncthreads();
  }
  if (t < 196) boff[t] = buf[t] - v;  // exclusive
}

__global__ __launch_bounds__(256) void k_s3(const int* __restrict__ deg,
                                            const int* __restrict__ boff,
                                            int* __restrict__ rs,
                                            int* __restrict__ cursor) {
  __shared__ int buf[256];
  const int t = threadIdx.x;
  const int i = blockIdx.x * 256 + t;
  int v = deg[i];
  buf[t] = v; __syncthreads();
  for (int off = 1; off < 256; off <<= 1) {
    int u = (t >= off) ? buf[t - off] : 0;
    __syncthreads();
    buf[t] += u;
    __syncthreads();
  }
  int r = boff[blockIdx.x] + buf[t] - v;
  if (i <= N_NODES) rs[i] = r;
  if (i < N_NODES) cursor[i] = r;
}

// Scatter: one 16B record per edge {dst, w01(half2), w23(half2), pad}.
// Single scattered dwordx4 store halves cache-line touches vs csr+wb split.
__global__ __launch_bounds__(256) void k_scatter(const int* __restrict__ ei,
                                                 int* __restrict__ cursor,
                                                 const float* __restrict__ el,
                                                 const float* __restrict__ er,
                                                 int4* __restrict__ recs) {
  int e = blockIdx.x * 256 + threadIdx.x;
  if (e < N_EDGES) {
    int s = ei[e];
    int d = ei[N_EDGES + e];
    int pos = atomicAdd(&cursor[s], 1);
    f32x4 a = ((const f32x4*)el)[s];   // L2-resident (800 KB)
    f32x4 b = ((const f32x4*)er)[d];
    float w[4];
    #pragma unroll
    for (int hh = 0; hh < 4; ++hh) {
      float t = a[hh] + b[hh];
      t = (t >= 0.f) ? t : 0.2f * t;
      w[hh] = __expf(t);
    }
    __half2 w01 = __floats2half2_rn(w[0], w[1]);
    __half2 w23 = __floats2half2_rn(w[2], w[3]);
    union { __half2 h; int i; } u01, u23;
    u01.h = w01; u23.h = w23;
    int4 r; r.x = d; r.y = u01.i; r.z = u23.i; r.w = 0;
    recs[pos] = r;
  }
}

// ---------------- Kernel 5: fused normalize + SpMM + ELU --------------------
// One wave per node, lane = output dim. Edge records carry dst + fp16 weights.
__global__ __launch_bounds__(256) void k_agg(const float* __restrict__ x,
    const int* __restrict__ rs, const int4* __restrict__ recs,
    const float* __restrict__ bvec, float* __restrict__ out) {
  const int node = (blockIdx.x * 256 + threadIdx.x) >> 6;
  const int lane = threadIdx.x & 63;
  if (node >= N_NODES) return;
  float n0 = 0.f, n1 = 0.f, n2 = 0.f, n3 = 0.f;
  float d0 = 0.f, d1 = 0.f, d2 = 0.f, d3 = 0.f;
  const int j0 = rs[node], j1 = rs[node + 1];
  #pragma unroll 4
  for (int j = j0; j < j1; ++j) {
    int4 rec = recs[j];               // 16B wave-uniform broadcast
    union { int i; __half2 h; } u01, u23;
    u01.i = rec.y; u23.i = rec.z;
    float2 f01 = __half22float2(u01.h);
    float2 f23 = __half22float2(u23.h);
    float xv = x[rec.x * 64 + lane];  // coalesced 256B gather
    d0 += f01.x; d1 += f01.y; d2 += f23.x; d3 += f23.y;
    n0 = fmaf(f01.x, xv, n0); n1 = fmaf(f01.y, xv, n1);
    n2 = fmaf(f23.x, xv, n2); n3 = fmaf(f23.y, xv, n3);
  }
  float bv = bvec[lane];
  size_t ob = (size_t)node * 256 + lane;
  float o;
  o = n0 / fmaxf(d0, 1e-12f) + bv; o = (o > 0.f) ? o : (__expf(o) - 1.f); out[ob      ] = o;
  o = n1 / fmaxf(d1, 1e-12f) + bv; o = (o > 0.f) ? o : (__expf(o) - 1.f); out[ob +  64] = o;
  o = n2 / fmaxf(d2, 1e-12f) + bv; o = (o > 0.f) ? o : (__expf(o) - 1.f); out[ob + 128] = o;
  o = n3 / fmaxf(d3, 1e-12f) + bv; o = (o > 0.f) ? o : (__expf(o) - 1.f); out[ob + 192] = o;
}

// ---------------- Launch ----------------------------------------------------
extern "C" void kernel_launch(void* const* d_in, const int* in_sizes, int n_in,
                              void* d_out, int out_size, void* d_ws, size_t ws_size,
                              hipStream_t stream) {
  const float* h  = (const float*)d_in[0];
  const float* W  = (const float*)d_in[1];
  const float* Wl = (const float*)d_in[2];
  const float* Wr = (const float*)d_in[3];
  const float* b  = (const float*)d_in[4];
  const int*   ei = (const int*)d_in[5];
  float* out = (float*)d_out;   // reference output dtype is float32

  char* ws = (char*)d_ws;
  float* x      = (float*)(ws + 0);          // 50000*64*4   = 12,800,000
  float* el     = (float*)(ws + 12800000);   // 50000*4*4    =    800,000
  float* er     = (float*)(ws + 13600000);   // 50000*4*4    =    800,000
  int*   deg    = (int*)  (ws + 14400000);   // 50176*4      =    200,704
  int*   cursor = (int*)  (ws + 14600704);   // 50176*4      =    200,704
  int*   rs     = (int*)  (ws + 14801408);   // 50001*4 (pad)=    200,960
  int*   bsum   = (int*)  (ws + 15002368);   // 256*4
  int*   boff   = (int*)  (ws + 15003392);   // 256*4
  int4*  recs   = (int4*) (ws + 15004416);   // 1.6M*16      = 25,600,000 (end ~40.6 MB)
  (void)ws_size; (void)in_sizes; (void)n_in; (void)out_size;

  hipMemsetAsync(deg, 0, 50176 * sizeof(int), stream);

  k_x      <<<782,   256, 0, stream>>>(h, W, x);
  k_eler   <<<782,   256, 0, stream>>>(x, Wl, Wr, el, er);
  k_hist   <<<6250,  256, 0, stream>>>(ei, deg);
  k_s1     <<<196,   256, 0, stream>>>(deg, bsum);
  k_s2     <<<1,     256, 0, stream>>>(bsum, boff);
  k_s3     <<<196,   256, 0, stream>>>(deg, boff, rs, cursor);
  k_scatter<<<6250,  256, 0, stream>>>(ei, cursor, el, er, recs);
  k_agg    <<<12500, 256, 0, stream>>>(x, rs, recs, b, out);
}